// Round 1
// baseline (414.855 us; speedup 1.0000x reference)
//
#include <hip/hip_runtime.h>
#include <cfloat>

// Problem constants (compile-time, from reference setup_inputs):
//   B=4096, C=10, H=30, W=30  -> HW=900 pixels/sample, 225 float4-groups/sample
#define CC   10
#define HWP  900
#define NBATCH 4096
#define NPIX_INV (1.0/3686400.0)   // 1/(B*H*W)

// Workspace layout (d_ws): facc[0]=sum(ce*w), facc[1]=sum((changed-t_changed)^2)
//                          iacc[0]=count(exact), iacc[1]=count(copy), iacc[2]=sum(missing)
__global__ __launch_bounds__(256) void per_sample_kernel(
    const float* __restrict__ pred,
    const float* __restrict__ target,
    const float* __restrict__ grid,
    float* __restrict__ facc,
    unsigned int* __restrict__ iacc)
{
    const int b   = blockIdx.x;
    const int tid = threadIdx.x;
    const size_t base = (size_t)b * (CC * HWP);

    float ce_w_sum = 0.f;
    int cnt_pt = 0;   // pixels where pred_idx != target_idx
    int cnt_tg = 0;   // pixels where target_idx != input_idx
    int cnt_pg = 0;   // pixels where pred_idx != input_idx
    unsigned pmask = 0, tmask = 0;  // 10-bit color presence masks

    if (tid < 225) {                 // 225 groups of 4 pixels = 900
        const int hw = tid * 4;      // 16B-aligned: base, c*900, 4*tid all %4==0 elems
        float p[CC][4];
        float pmax[4], tmax[4], gmax[4], pat[4];
        int   pidx[4], tidx[4], gidx[4];
        #pragma unroll
        for (int k = 0; k < 4; ++k) {
            pmax[k] = -FLT_MAX; tmax[k] = -FLT_MAX; gmax[k] = -FLT_MAX;
            pidx[k] = 0; tidx[k] = 0; gidx[k] = 0; pat[k] = 0.f;
        }
        #pragma unroll
        for (int c = 0; c < CC; ++c) {
            const float4 pv = *(const float4*)(pred   + base + c * HWP + hw);
            const float4 tv = *(const float4*)(target + base + c * HWP + hw);
            const float4 gv = *(const float4*)(grid   + base + c * HWP + hw);
            const float pa[4] = {pv.x, pv.y, pv.z, pv.w};
            const float ta[4] = {tv.x, tv.y, tv.z, tv.w};
            const float ga[4] = {gv.x, gv.y, gv.z, gv.w};
            #pragma unroll
            for (int k = 0; k < 4; ++k) {
                p[c][k] = pa[k];
                if (pa[k] > pmax[k]) { pmax[k] = pa[k]; pidx[k] = c; }
                if (ta[k] > tmax[k]) { tmax[k] = ta[k]; tidx[k] = c; pat[k] = pa[k]; }
                if (ga[k] > gmax[k]) { gmax[k] = ga[k]; gidx[k] = c; }
            }
        }
        #pragma unroll
        for (int k = 0; k < 4; ++k) {
            float s = 0.f;
            #pragma unroll
            for (int c = 0; c < CC; ++c) s += __expf(p[c][k] - pmax[k]);
            const float ce  = pmax[k] + __logf(s) - pat[k];   // lse - pred[target_idx]
            const int   inc = (pidx[k] != tidx[k]);
            ce_w_sum += ce * (1.f + 2.f * (float)inc);
            cnt_pt += inc;
            cnt_tg += (tidx[k] != gidx[k]);
            cnt_pg += (pidx[k] != gidx[k]);
            pmask  |= (1u << pidx[k]);
            tmask  |= (1u << tidx[k]);
        }
    }

    // wave-64 shuffle reduction
    #pragma unroll
    for (int off = 32; off > 0; off >>= 1) {
        ce_w_sum += __shfl_down(ce_w_sum, off);
        cnt_pt   += __shfl_down(cnt_pt, off);
        cnt_tg   += __shfl_down(cnt_tg, off);
        cnt_pg   += __shfl_down(cnt_pg, off);
        pmask    |= __shfl_down(pmask, off);
        tmask    |= __shfl_down(tmask, off);
    }

    __shared__ float    s_ce[4];
    __shared__ int      s_pt[4], s_tg[4], s_pg[4];
    __shared__ unsigned s_pm[4], s_tm[4];
    const int wave = tid >> 6, lane = tid & 63;
    if (lane == 0) {
        s_ce[wave] = ce_w_sum; s_pt[wave] = cnt_pt; s_tg[wave] = cnt_tg;
        s_pg[wave] = cnt_pg;   s_pm[wave] = pmask;  s_tm[wave] = tmask;
    }
    __syncthreads();
    if (tid == 0) {
        float ce = 0.f; int pt = 0, tg = 0, pg = 0; unsigned pm = 0, tm = 0;
        #pragma unroll
        for (int w = 0; w < 4; ++w) {
            ce += s_ce[w]; pt += s_pt[w]; tg += s_tg[w]; pg += s_pg[w];
            pm |= s_pm[w]; tm |= s_tm[w];
        }
        atomicAdd(&facc[0], ce);
        const float d = (float)(pg - tg) * (1.0f / 900.0f);  // changed - t_changed
        atomicAdd(&facc[1], d * d);
        if (pt == 0)           atomicAdd(&iacc[0], 1u);       // exact match
        if (tg > 0 && pg == 0) atomicAdd(&iacc[1], 1u);       // should_not_copy & did_copy
        const unsigned miss = tm & ~pm & 0x3FFu;
        if (miss)              atomicAdd(&iacc[2], (unsigned)__popc(miss));
    }
}

__global__ void finalize_kernel(const float* __restrict__ facc,
                                const unsigned* __restrict__ iacc,
                                float* __restrict__ out)
{
    if (threadIdx.x == 0 && blockIdx.x == 0) {
        const float ce_mean        = (float)((double)facc[0] * NPIX_INV);
        const float ce_loss        = ce_mean + 0.5f * (float)iacc[2];
        const float exact_bonus    = -10.0f * ((float)iacc[0] / (float)NBATCH);
        const float copy_penalty   =   5.0f * ((float)iacc[1] / (float)NBATCH);
        const float transform_diff = (facc[1] / (float)NBATCH) * 2.0f;
        out[0] = ce_loss + exact_bonus + copy_penalty + transform_diff;
        out[1] = ce_loss;
        out[2] = exact_bonus;
        out[3] = copy_penalty;
        out[4] = transform_diff;
        out[5] = (float)iacc[0];   // jnp.sum(exact)
    }
}

extern "C" void kernel_launch(void* const* d_in, const int* in_sizes, int n_in,
                              void* d_out, int out_size, void* d_ws, size_t ws_size,
                              hipStream_t stream) {
    const float* pred   = (const float*)d_in[0];
    const float* target = (const float*)d_in[1];
    const float* grid   = (const float*)d_in[2];
    float*    out  = (float*)d_out;
    float*    facc = (float*)d_ws;
    unsigned* iacc = (unsigned*)((char*)d_ws + 16);

    hipMemsetAsync(d_ws, 0, 64, stream);
    per_sample_kernel<<<NBATCH, 256, 0, stream>>>(pred, target, grid, facc, iacc);
    finalize_kernel<<<1, 64, 0, stream>>>(facc, iacc, out);
}